// Round 7
// baseline (118.916 us; speedup 1.0000x reference)
//
#include <hip/hip_runtime.h>
#include <cstddef>

// Problem constants (fixed by the reference): B=4096, T=204800, D=32, H=64
#define DICE_EPS 1e-10f

typedef __attribute__((ext_vector_type(8))) short bf16x8;  // MFMA A/B frag
typedef __attribute__((ext_vector_type(4))) float f32x4;   // MFMA C/D frag
typedef __attribute__((ext_vector_type(4))) unsigned int u32x4;

// Truncating fp32 -> (hi, lo) bf16 split: x ≈ hi + lo with |err| ~ 2^-17 |x|.
__device__ inline void f2bf_split(float x, short& hi, short& lo) {
  const unsigned u = __float_as_uint(x);
  hi = (short)(u >> 16);
  const float rem = x - __uint_as_float(u & 0xffff0000u);  // exact
  lo = (short)(__float_as_uint(rem) >> 16);
}

// DPP-based add from a statically-permuted lane (VALU pipe, ~2 cyc latency,
// vs ds_bpermute's ~30-40 cyc on the LDS pipe).
#define DPP_ADD(v, ctrl)                                             \
  ((v) + __int_as_float(__builtin_amdgcn_update_dpp(                 \
             0, __float_as_int(v), (ctrl), 0xF, 0xF, true)))
// Full sum over each 16-lane row: xor1, xor2 (quad_perm), ror8, ror4.
#define REDUCE16(v)            \
  do {                         \
    v = DPP_ADD(v, 0xB1);      \
    v = DPP_ADD(v, 0x4E);      \
    v = DPP_ADD(v, 0x128);     \
    v = DPP_ADD(v, 0x124);     \
  } while (0)

// ---------------------------------------------------------------------------
// Kernel 1 (fused): seg_starts + MFMA M-frag producer (LDS-bounced coalesced
// stores) + per-candidate base vector.
//   M_all[r][(i,k)] = cand[r][:] @ W1o[:][(i,k)] + W1b[i][k]  (bf16 hi/lo
//   planes in the attention B-frag layout), and
//   Base[r][k] = b1[k] + cand[r][:] @ W1c[:][k]  (fp32).
// Grid: (B/16)*4 = 1024 blocks; block covers candidate group r0..r0+15 and
// col-tile quarter z (tiles np = 32z..32z+31, 8 per wave). z==0 blocks also
// compute Base (one extra MFMA trio per wave). Blocks with blockIdx*256 < T
// also compute seg[]: seg[r] = first t with row_ids[t] >= r; seg[B] = T.
// ---------------------------------------------------------------------------
__global__ __launch_bounds__(256) void precompute_Mfrag(
    const float* __restrict__ cand, const float* __restrict__ W1,
    const float* __restrict__ b1, const int* __restrict__ row_ids,
    unsigned short* __restrict__ Mhi, unsigned short* __restrict__ Mlo,
    float* __restrict__ Base, int* __restrict__ seg, int T, int B) {
  // --- seg part (first ceil(T/256) blocks) ---
  {
    const int t = blockIdx.x * 256 + threadIdx.x;
    if (t < T) {
      const int b = row_ids[t];
      const int a = (t == 0) ? 0 : row_ids[t - 1];
      if (t == 0) seg[0] = 0;
      for (int r = a + 1; r <= b; r++) seg[r] = t;
      if (t == T - 1)
        for (int r = b + 1; r <= B; r++) seg[r] = T;
    }
  }

  // --- producer part ---
  const int lane = threadIdx.x & 63;
  const int wv = threadIdx.x >> 6;
  const int r0 = (blockIdx.x >> 2) * 16;    // candidate group base
  const int z = blockIdx.x & 3;             // col-tile quarter
  const int q = z * 4 + wv;                 // wave id 0..15 within group
  const int c = lane & 15, g = lane >> 4;

  // Block image: [plane][ (rr*4+nn)*16 + c ][ jj2 ] shorts = 2 x 16 KB.
  __shared__ __align__(16) unsigned short limg[2][16 * 4 * 16 * 8];

  // A-frag: A[m][j=8g+jj] = cand[r0+m][8g+jj], m = c  (hi/lo split)
  bf16x8 Ahi, Alo;
  {
    const f32x4* ap =
        reinterpret_cast<const f32x4*>(cand + (size_t)(r0 + c) * 32 + 8 * g);
    const f32x4 a0 = ap[0], a1 = ap[1];
    const float av[8] = {a0.x, a0.y, a0.z, a0.w, a1.x, a1.y, a1.z, a1.w};
#pragma unroll
    for (int j = 0; j < 8; j++) {
      short h, l;
      f2bf_split(av[j], h, l);
      Ahi[j] = h; Alo[j] = l;
    }
  }

#pragma unroll
  for (int m = 0; m < 8; m++) {
    const int np = 8 * q + m;           // col-tile 32z .. 32z+31
    const int i = np >> 2;              // 0..31
    const int k = 16 * (np & 3) + c;    // 0..63
    // B-frag: B[j=8g+jj][col=c] = W1[(64 + 32*i + 8g + jj)*64 + k]
    const float* bp = W1 + (size_t)(64 + 32 * i + 8 * g) * 64 + k;
    bf16x8 Bhi, Blo;
#pragma unroll
    for (int jj = 0; jj < 8; jj++) {
      short h, l;
      f2bf_split(bp[(size_t)jj * 64], h, l);
      Bhi[jj] = h; Blo[jj] = l;
    }
    f32x4 Cz = {0.f, 0.f, 0.f, 0.f};
    Cz = __builtin_amdgcn_mfma_f32_16x16x32_bf16(Alo, Bhi, Cz, 0, 0, 0);
    Cz = __builtin_amdgcn_mfma_f32_16x16x32_bf16(Ahi, Blo, Cz, 0, 0, 0);
    Cz = __builtin_amdgcn_mfma_f32_16x16x32_bf16(Ahi, Bhi, Cz, 0, 0, 0);
    const float bias = W1[(size_t)(32 + i) * 64 + k];  // W1b[i][k]

    const int nn = np & 3;
    const int jj2 = (np >> 2) & 7;
    // C layout: lane (c,g) reg p holds C[row=4g+p][col=c]; row = rr (cand).
#pragma unroll
    for (int p = 0; p < 4; p++) {
      const float v = Cz[p] + bias;
      const int rr = 4 * g + p;
      const int idx = ((rr * 4 + nn) * 16 + c) * 8 + jj2;
      short h, l;
      f2bf_split(v, h, l);
      limg[0][idx] = (unsigned short)h;
      limg[1][idx] = (unsigned short)l;
    }
  }

  // Base (z==0 blocks only): wave wv handles k-tile n=wv.
  if (z == 0) {
    const int k = 16 * wv + c;
    const float* bp = W1 + (size_t)(8 * g) * 64 + k;  // W1c rows j
    bf16x8 Bhi, Blo;
#pragma unroll
    for (int jj = 0; jj < 8; jj++) {
      short h, l;
      f2bf_split(bp[(size_t)jj * 64], h, l);
      Bhi[jj] = h; Blo[jj] = l;
    }
    f32x4 Cz = {0.f, 0.f, 0.f, 0.f};
    Cz = __builtin_amdgcn_mfma_f32_16x16x32_bf16(Alo, Bhi, Cz, 0, 0, 0);
    Cz = __builtin_amdgcn_mfma_f32_16x16x32_bf16(Ahi, Blo, Cz, 0, 0, 0);
    Cz = __builtin_amdgcn_mfma_f32_16x16x32_bf16(Ahi, Bhi, Cz, 0, 0, 0);
    const float bias = b1[k];
#pragma unroll
    for (int p = 0; p < 4; p++)
      Base[(size_t)(r0 + 4 * g + p) * 64 + k] = Cz[p] + bias;
  }
  __syncthreads();

  // Coalesced copy-out: 1024 uint4 per plane, 256B-contiguous runs.
  {
    const u32x4* src_h = reinterpret_cast<const u32x4*>(limg[0]);
    const u32x4* src_l = reinterpret_cast<const u32x4*>(limg[1]);
    u32x4* dst_h = reinterpret_cast<u32x4*>(Mhi);
    u32x4* dst_l = reinterpret_cast<u32x4*>(Mlo);
#pragma unroll
    for (int it = 0; it < 4; it++) {
      const int u = it * 256 + threadIdx.x;
      const size_t dst = (size_t)(r0 * 4 + (u >> 4)) * 64 + z * 16 + (u & 15);
      dst_h[dst] = src_h[u];
      dst_l[dst] = src_l[u];
    }
  }
}

// ---------------------------------------------------------------------------
// Kernel 2: one WAVE per candidate, 2 candidates per 128-thread block.
//   2 x 16-row MFMA tiles in flight per iteration (independent latency
//   chains). All reductions via DPP (VALU pipe); only the w-broadcast uses
//   one ds_bpermute per tile. Zero LDS.
// ---------------------------------------------------------------------------
__global__ __launch_bounds__(128) void attention_mfma(
    const float* __restrict__ behavior, const float* __restrict__ alpha,
    const float* __restrict__ W2, const float* __restrict__ b2,
    const unsigned short* __restrict__ Mhi,
    const unsigned short* __restrict__ Mlo, const float* __restrict__ Base,
    const int* __restrict__ seg, float* __restrict__ out) {
  const int lane = threadIdx.x & 63;
  const int wid = threadIdx.x >> 6;
  const int r = blockIdx.x * 2 + wid;  // this wave's candidate
  const int c = lane & 15;             // col-in-tile (B/C) == row m (A)
  const int g = lane >> 4;             // 16-lane group

  const int t0 = seg[r];
  const int t1 = seg[r + 1];

  // --- B fragments: direct coalesced frag-layout loads (4x dwordx4 each). ---
  bf16x8 Bhi[4], Blo[4];
  {
    const bf16x8* mh =
        reinterpret_cast<const bf16x8*>(Mhi) + (size_t)r * 4 * 64 + lane;
    const bf16x8* ml =
        reinterpret_cast<const bf16x8*>(Mlo) + (size_t)r * 4 * 64 + lane;
#pragma unroll
    for (int n = 0; n < 4; n++) {
      Bhi[n] = mh[(size_t)n * 64];
      Blo[n] = ml[(size_t)n * 64];
    }
  }

  // --- per-lane col constants for cols 16n+c ---
  float base_n[4], al_n[4], w2_n[4];
#pragma unroll
  for (int n = 0; n < 4; n++) {
    base_n[n] = Base[(size_t)r * 64 + 16 * n + c];
    al_n[n] = alpha[16 * n + c];
    w2_n[n] = W2[16 * n + c];
  }
  const float b2v = b2[0];
  const int wsrc = ((c >> 2) << 4) | (c & 3);  // bpermute source for w[row=c]

  float acc[8];
#pragma unroll
  for (int jj = 0; jj < 8; jj++) acc[jj] = 0.f;

  for (int tb = t0; tb < t1; tb += 32) {
    // Two independent 16-row tiles u=0,1: rows tb+16u+c.
    f32x4 a0[2], a1[2];
    bf16x8 Ahi[2], Alo[2];
#pragma unroll
    for (int u = 0; u < 2; u++) {
      const int trow = tb + 16 * u + c;
      f32x4 x0 = {0.f, 0.f, 0.f, 0.f}, x1 = {0.f, 0.f, 0.f, 0.f};
      if (trow < t1) {
        const f32x4* bp =
            reinterpret_cast<const f32x4*>(behavior + (size_t)trow * 32 + 8 * g);
        x0 = bp[0];
        x1 = bp[1];
      }
      a0[u] = x0;
      a1[u] = x1;
      const float av[8] = {x0.x, x0.y, x0.z, x0.w, x1.x, x1.y, x1.z, x1.w};
#pragma unroll
      for (int j = 0; j < 8; j++) {
        short h, l;
        f2bf_split(av[j], h, l);
        Ahi[u][j] = h; Alo[u][j] = l;
      }
    }

    // C[u][n] = A_u * B[n] (hi/lo cross terms, lolo dropped), then += base.
    f32x4 C[2][4];
#pragma unroll
    for (int u = 0; u < 2; u++)
#pragma unroll
      for (int n = 0; n < 4; n++) {
        f32x4 cz = {0.f, 0.f, 0.f, 0.f};
        cz = __builtin_amdgcn_mfma_f32_16x16x32_bf16(Alo[u], Bhi[n], cz, 0, 0, 0);
        cz = __builtin_amdgcn_mfma_f32_16x16x32_bf16(Ahi[u], Blo[n], cz, 0, 0, 0);
        cz = __builtin_amdgcn_mfma_f32_16x16x32_bf16(Ahi[u], Bhi[n], cz, 0, 0, 0);
        C[u][n] = cz;
      }

    // h = C + base; raw moments per row (row = 4g+j within tile u).
    float s[2][4], s2[2][4];
#pragma unroll
    for (int u = 0; u < 2; u++)
#pragma unroll
      for (int j = 0; j < 4; j++) {
        float ss = 0.f, qq = 0.f;
#pragma unroll
        for (int n = 0; n < 4; n++) {
          const float h = C[u][n][j] + base_n[n];
          C[u][n][j] = h;
          ss += h;
          qq += h * h;
        }
        s[u][j] = ss;
        s2[u][j] = qq;
      }
    // 16-lane-row sums via DPP (16 independent 4-stage chains, VALU pipe).
#pragma unroll
    for (int u = 0; u < 2; u++)
#pragma unroll
      for (int j = 0; j < 4; j++) {
        REDUCE16(s[u][j]);
        REDUCE16(s2[u][j]);
      }

    // Dice + H->1 projection partials.
    float wp[2][4];
#pragma unroll
    for (int u = 0; u < 2; u++)
#pragma unroll
      for (int j = 0; j < 4; j++) {
        const float mean = s[u][j] * (1.f / 64.f);
        const float var = fmaxf(s2[u][j] * (1.f / 64.f) - mean * mean, 0.f);
        const float inv = __builtin_amdgcn_rsqf(var + DICE_EPS);
        float w = 0.f;
#pragma unroll
        for (int n = 0; n < 4; n++) {
          const float h = C[u][n][j];
          const float e = __expf((mean - h) * inv);
          const float p = __builtin_amdgcn_rcpf(1.f + e);
          const float hd = (al_n[n] + p * (1.f - al_n[n])) * h;
          w = fmaf(hd, w2_n[n], w);
        }
        wp[u][j] = w;
      }
#pragma unroll
    for (int u = 0; u < 2; u++)
#pragma unroll
      for (int j = 0; j < 4; j++) REDUCE16(wp[u][j]);

    // w for row m=c lives in lane (c&3, c>>2) as wp[c&3]: select + bpermute.
#pragma unroll
    for (int u = 0; u < 2; u++) {
      const float t01 = (c & 1) ? wp[u][1] : wp[u][0];
      const float t23 = (c & 1) ? wp[u][3] : wp[u][2];
      const float vsel = (c & 2) ? t23 : t01;
      const float w = __shfl(vsel, wsrc, 64) + b2v;
      acc[0] = fmaf(a0[u].x, w, acc[0]);
      acc[1] = fmaf(a0[u].y, w, acc[1]);
      acc[2] = fmaf(a0[u].z, w, acc[2]);
      acc[3] = fmaf(a0[u].w, w, acc[3]);
      acc[4] = fmaf(a1[u].x, w, acc[4]);
      acc[5] = fmaf(a1[u].y, w, acc[5]);
      acc[6] = fmaf(a1[u].z, w, acc[6]);
      acc[7] = fmaf(a1[u].w, w, acc[7]);
    }
  }

  // Sum over the 16 rows (c-lanes) via DPP, once per candidate.
#pragma unroll
  for (int jj = 0; jj < 8; jj++) REDUCE16(acc[jj]);
  if (c == 0) {  // lanes 0,16,32,48 -> d = 8g .. 8g+7
    f32x4 o0 = {acc[0], acc[1], acc[2], acc[3]};
    f32x4 o1 = {acc[4], acc[5], acc[6], acc[7]};
    f32x4* op = reinterpret_cast<f32x4*>(out + (size_t)r * 32 + 8 * g);
    op[0] = o0;
    op[1] = o1;
  }
}

// ---------------------------------------------------------------------------
extern "C" void kernel_launch(void* const* d_in, const int* in_sizes, int n_in,
                              void* d_out, int out_size, void* d_ws, size_t ws_size,
                              hipStream_t stream) {
  const float* cand     = (const float*)d_in[0];
  const float* behavior = (const float*)d_in[1];
  const int*   row_ids  = (const int*)d_in[2];
  const float* W1       = (const float*)d_in[3];
  const float* b1       = (const float*)d_in[4];
  const float* alpha    = (const float*)d_in[5];
  const float* W2       = (const float*)d_in[6];
  const float* b2       = (const float*)d_in[7];
  float* out = (float*)d_out;

  const int B = in_sizes[0] / 32;  // 4096
  const int T = in_sizes[2];       // 204800

  // ws: Mhi (16.8 MB), Mlo (16.8 MB), Base (1 MB), seg (B+1 ints)
  unsigned short* Mhi = (unsigned short*)d_ws;
  unsigned short* Mlo = Mhi + (size_t)B * 2048;
  float* Base = (float*)(Mlo + (size_t)B * 2048);
  int* seg = (int*)(Base + (size_t)B * 64);

  const int nblk = max((B / 16) * 4, (T + 255) / 256);
  precompute_Mfrag<<<nblk, 256, 0, stream>>>(cand, W1, b1, row_ids, Mhi, Mlo,
                                             Base, seg, T, B);
  attention_mfma<<<B / 2, 128, 0, stream>>>(behavior, alpha, W2, b2, Mhi, Mlo,
                                            Base, seg, out);
}

// Round 8
// 109.046 us; speedup vs baseline: 1.0905x; 1.0905x over previous
//
#include <hip/hip_runtime.h>
#include <cstddef>

// Problem constants (fixed by the reference): B=4096, T=204800, D=32, H=64
#define DICE_EPS 1e-10f

typedef __attribute__((ext_vector_type(8))) short bf16x8;  // MFMA A/B frag
typedef __attribute__((ext_vector_type(4))) float f32x4;   // MFMA C/D frag

// Truncating fp32 -> (hi, lo) bf16 split: x ≈ hi + lo with |err| ~ 2^-17 |x|.
__device__ inline void f2bf_split(float x, short& hi, short& lo) {
  const unsigned u = __float_as_uint(x);
  hi = (short)(u >> 16);
  const float rem = x - __uint_as_float(u & 0xffff0000u);  // exact
  lo = (short)(__float_as_uint(rem) >> 16);
}

// DPP-based add from a statically-permuted lane (VALU pipe, ~2 cyc latency).
#define DPP_ADD(v, ctrl)                                             \
  ((v) + __int_as_float(__builtin_amdgcn_update_dpp(                 \
             0, __float_as_int(v), (ctrl), 0xF, 0xF, true)))
// Full sum over each 16-lane row: xor1, xor2 (quad_perm), ror8, ror4.
#define REDUCE16(v)            \
  do {                         \
    v = DPP_ADD(v, 0xB1);      \
    v = DPP_ADD(v, 0x4E);      \
    v = DPP_ADD(v, 0x128);     \
    v = DPP_ADD(v, 0x124);     \
  } while (0)

// ---------------------------------------------------------------------------
// Single fused kernel. Block = 1024 threads = 16 waves = 16 candidates
// (grid = B/16 = 256 blocks = 1 block/CU). No workspace, no global M.
//
// Phase A (producer): wave q computes col-tiles np = 8q..8q+7 of
//   M[r][i][k] = W1[(32+i)*64+k] + sum_j cand[r][j]*W1[(64+i*32+j)*64+k]
// for all 16 candidates via 16x16x32 bf16 MFMA (hi/lo split, lolo dropped),
// holding the 32 results in registers. The bf16 frag image is staged through
// a 64 KB LDS buffer one plane at a time (write-hi, sync, read-hi frags,
// sync, write-lo, sync, read-lo frags) -> M never touches global memory.
//
// Phase B (attention): wave w owns candidate r0+w. 16 behavior rows per MFMA
// tile; dice stats via DPP 16-lane reductions; w-broadcast via one shfl.
// Segment bounds via per-wave uniform binary search on sorted row_ids.
// ---------------------------------------------------------------------------
__global__ __launch_bounds__(1024) void attention_fused(
    const float* __restrict__ cand, const float* __restrict__ behavior,
    const int* __restrict__ row_ids, const float* __restrict__ W1,
    const float* __restrict__ b1, const float* __restrict__ alpha,
    const float* __restrict__ W2, const float* __restrict__ b2,
    float* __restrict__ out, int T, int B) {
  const int lane = threadIdx.x & 63;
  const int w = threadIdx.x >> 6;  // wave id 0..15: producer q / candidate
  const int r0 = blockIdx.x * 16;
  const int r = r0 + w;
  const int c = lane & 15;  // A-row / C-col index
  const int g = lane >> 4;  // 16-lane group

  __shared__ __align__(16) unsigned short img[16 * 2048];  // 64 KB, 1 plane

  // ---- segment bounds: wave-uniform binary search (sorted row_ids) ----
  int t0, t1;
  {
    int lo = 0, hi = T;
    while (lo < hi) { int mid = (lo + hi) >> 1; if (row_ids[mid] < r) lo = mid + 1; else hi = mid; }
    t0 = lo;
    hi = T;
    while (lo < hi) { int mid = (lo + hi) >> 1; if (row_ids[mid] < r + 1) lo = mid + 1; else hi = mid; }
    t1 = lo;
  }

  // ---- Phase A: producer ----
  // A-frag: A[m=c][j=8g+jj] = cand[r0+c][8g+jj]  (hi/lo split)
  bf16x8 Ahi, Alo;
  {
    const f32x4* ap =
        reinterpret_cast<const f32x4*>(cand + (size_t)(r0 + c) * 32 + 8 * g);
    const f32x4 a0 = ap[0], a1 = ap[1];
    const float av[8] = {a0.x, a0.y, a0.z, a0.w, a1.x, a1.y, a1.z, a1.w};
#pragma unroll
    for (int j = 0; j < 8; j++) {
      short h, l;
      f2bf_split(av[j], h, l);
      Ahi[j] = h; Alo[j] = l;
    }
  }

  float v[8][4];  // per-tile C column values (32 VGPRs)
#pragma unroll
  for (int m = 0; m < 8; m++) {
    const int np = 8 * w + m;         // col-tile 0..127
    const int i = np >> 2;            // 0..31
    const int k = 16 * (np & 3) + c;  // 0..63
    // B-frag: B[j=8g+jj][col=c] = W1[(64 + 32*i + 8g + jj)*64 + k]
    const float* bp = W1 + (size_t)(64 + 32 * i + 8 * g) * 64 + k;
    bf16x8 Bh, Bl;
#pragma unroll
    for (int jj = 0; jj < 8; jj++) {
      short h, l;
      f2bf_split(bp[(size_t)jj * 64], h, l);
      Bh[jj] = h; Bl[jj] = l;
    }
    f32x4 Cz = {0.f, 0.f, 0.f, 0.f};
    Cz = __builtin_amdgcn_mfma_f32_16x16x32_bf16(Alo, Bh, Cz, 0, 0, 0);
    Cz = __builtin_amdgcn_mfma_f32_16x16x32_bf16(Ahi, Bl, Cz, 0, 0, 0);
    Cz = __builtin_amdgcn_mfma_f32_16x16x32_bf16(Ahi, Bh, Cz, 0, 0, 0);
    const float bias = W1[(size_t)(32 + i) * 64 + k];  // W1b[i][k]
#pragma unroll
    for (int p = 0; p < 4; p++) v[m][p] = Cz[p] + bias;
  }

  // Frag-image index for (tile m, C-reg p) of this lane:
  //   cand rr = 4g+p; chunk = (np&3); lane' = 16*(np>>5) + c; jj2 = (np>>2)&7
  //   idx = rr*2048 + ((np&3)*64 + lane')*8 + jj2
  // Stage hi plane, consume, then lo plane (reusing the same 64 KB).
  bf16x8 Bhi[4], Blo[4];
#pragma unroll
  for (int m = 0; m < 8; m++) {
    const int np = 8 * w + m;
    const int base = ((np & 3) * 64 + 16 * (np >> 5) + c) * 8 + ((np >> 2) & 7);
#pragma unroll
    for (int p = 0; p < 4; p++) {
      const unsigned u = __float_as_uint(v[m][p]);
      img[(4 * g + p) * 2048 + base] = (unsigned short)(u >> 16);
    }
  }
  __syncthreads();
#pragma unroll
  for (int n = 0; n < 4; n++)
    Bhi[n] = *reinterpret_cast<const bf16x8*>(&img[w * 2048 + (n * 64 + lane) * 8]);
  __syncthreads();
#pragma unroll
  for (int m = 0; m < 8; m++) {
    const int np = 8 * w + m;
    const int base = ((np & 3) * 64 + 16 * (np >> 5) + c) * 8 + ((np >> 2) & 7);
#pragma unroll
    for (int p = 0; p < 4; p++) {
      const float x = v[m][p];
      const float rem = x - __uint_as_float(__float_as_uint(x) & 0xffff0000u);
      img[(4 * g + p) * 2048 + base] = (unsigned short)(__float_as_uint(rem) >> 16);
    }
  }
  __syncthreads();
#pragma unroll
  for (int n = 0; n < 4; n++)
    Blo[n] = *reinterpret_cast<const bf16x8*>(&img[w * 2048 + (n * 64 + lane) * 8]);

  // ---- per-lane col constants for cols 16n+c (W1c region is L1/L2-hot) ----
  float base_n[4], al_n[4], w2_n[4];
#pragma unroll
  for (int n = 0; n < 4; n++) {
    base_n[n] = b1[16 * n + c];
    al_n[n] = alpha[16 * n + c];
    w2_n[n] = W2[16 * n + c];
  }
  for (int d = 0; d < 32; d++) {
    const float cd = cand[(size_t)r * 32 + d];  // wave-uniform -> s_load
#pragma unroll
    for (int n = 0; n < 4; n++)
      base_n[n] = fmaf(cd, W1[(size_t)d * 64 + 16 * n + c], base_n[n]);
  }
  const float b2v = b2[0];
  const int wsrc = ((c >> 2) << 4) | (c & 3);  // shfl source for w[row=c]

  float acc[8];
#pragma unroll
  for (int jj = 0; jj < 8; jj++) acc[jj] = 0.f;

  // ---- Phase B: attention over this wave's segment, 16 rows per tile ----
  for (int tb = t0; tb < t1; tb += 16) {
    const int trow = tb + c;
    f32x4 a0 = {0.f, 0.f, 0.f, 0.f}, a1 = {0.f, 0.f, 0.f, 0.f};
    if (trow < t1) {
      const f32x4* bp =
          reinterpret_cast<const f32x4*>(behavior + (size_t)trow * 32 + 8 * g);
      a0 = bp[0];
      a1 = bp[1];
    }
    bf16x8 Fhi, Flo;
    {
      const float av[8] = {a0.x, a0.y, a0.z, a0.w, a1.x, a1.y, a1.z, a1.w};
#pragma unroll
      for (int j = 0; j < 8; j++) {
        short h, l;
        f2bf_split(av[j], h, l);
        Fhi[j] = h; Flo[j] = l;
      }
    }

    f32x4 C[4];
#pragma unroll
    for (int n = 0; n < 4; n++) {
      f32x4 cz = {0.f, 0.f, 0.f, 0.f};
      cz = __builtin_amdgcn_mfma_f32_16x16x32_bf16(Flo, Bhi[n], cz, 0, 0, 0);
      cz = __builtin_amdgcn_mfma_f32_16x16x32_bf16(Fhi, Blo[n], cz, 0, 0, 0);
      cz = __builtin_amdgcn_mfma_f32_16x16x32_bf16(Fhi, Bhi[n], cz, 0, 0, 0);
      C[n] = cz;
    }

    // h = C + base; raw moments per row (row = 4g+j).
    float s[4], s2[4];
#pragma unroll
    for (int j = 0; j < 4; j++) {
      float ss = 0.f, qq = 0.f;
#pragma unroll
      for (int n = 0; n < 4; n++) {
        const float h = C[n][j] + base_n[n];
        C[n][j] = h;
        ss += h;
        qq += h * h;
      }
      s[j] = ss;
      s2[j] = qq;
    }
#pragma unroll
    for (int j = 0; j < 4; j++) {
      REDUCE16(s[j]);
      REDUCE16(s2[j]);
    }

    float wp[4];
#pragma unroll
    for (int j = 0; j < 4; j++) {
      const float mean = s[j] * (1.f / 64.f);
      const float var = fmaxf(s2[j] * (1.f / 64.f) - mean * mean, 0.f);
      const float inv = __builtin_amdgcn_rsqf(var + DICE_EPS);
      float ww = 0.f;
#pragma unroll
      for (int n = 0; n < 4; n++) {
        const float h = C[n][j];
        const float e = __expf((mean - h) * inv);
        const float p = __builtin_amdgcn_rcpf(1.f + e);
        const float hd = (al_n[n] + p * (1.f - al_n[n])) * h;
        ww = fmaf(hd, w2_n[n], ww);
      }
      wp[j] = ww;
    }
#pragma unroll
    for (int j = 0; j < 4; j++) REDUCE16(wp[j]);

    // w for row m=c lives in lane group (c>>2) as wp[c&3]: select + shfl.
    const float t01 = (c & 1) ? wp[1] : wp[0];
    const float t23 = (c & 1) ? wp[3] : wp[2];
    const float vsel = (c & 2) ? t23 : t01;
    const float wv = __shfl(vsel, wsrc, 64) + b2v;

    acc[0] = fmaf(a0.x, wv, acc[0]);
    acc[1] = fmaf(a0.y, wv, acc[1]);
    acc[2] = fmaf(a0.z, wv, acc[2]);
    acc[3] = fmaf(a0.w, wv, acc[3]);
    acc[4] = fmaf(a1.x, wv, acc[4]);
    acc[5] = fmaf(a1.y, wv, acc[5]);
    acc[6] = fmaf(a1.z, wv, acc[6]);
    acc[7] = fmaf(a1.w, wv, acc[7]);
  }

  // Sum over the 16 rows (c-lanes) via DPP, once per candidate.
#pragma unroll
  for (int jj = 0; jj < 8; jj++) REDUCE16(acc[jj]);
  if (c == 0) {  // lanes 0,16,32,48 -> d = 8g .. 8g+7
    f32x4 o0 = {acc[0], acc[1], acc[2], acc[3]};
    f32x4 o1 = {acc[4], acc[5], acc[6], acc[7]};
    f32x4* op = reinterpret_cast<f32x4*>(out + (size_t)r * 32 + 8 * g);
    op[0] = o0;
    op[1] = o1;
  }
}

// ---------------------------------------------------------------------------
extern "C" void kernel_launch(void* const* d_in, const int* in_sizes, int n_in,
                              void* d_out, int out_size, void* d_ws, size_t ws_size,
                              hipStream_t stream) {
  const float* cand     = (const float*)d_in[0];
  const float* behavior = (const float*)d_in[1];
  const int*   row_ids  = (const int*)d_in[2];
  const float* W1       = (const float*)d_in[3];
  const float* b1       = (const float*)d_in[4];
  const float* alpha    = (const float*)d_in[5];
  const float* W2       = (const float*)d_in[6];
  const float* b2       = (const float*)d_in[7];
  float* out = (float*)d_out;

  const int B = in_sizes[0] / 32;  // 4096
  const int T = in_sizes[2];       // 204800

  attention_fused<<<B / 16, 1024, 0, stream>>>(cand, behavior, row_ids, W1, b1,
                                               alpha, W2, b2, out, T, B);
}

// Round 9
// 102.055 us; speedup vs baseline: 1.1652x; 1.0685x over previous
//
#include <hip/hip_runtime.h>
#include <cstddef>

// Problem constants (fixed by the reference): B=4096, T=204800, D=32, H=64
#define DICE_EPS 1e-10f

typedef __attribute__((ext_vector_type(8))) short bf16x8;  // MFMA A/B frag
typedef __attribute__((ext_vector_type(4))) float f32x4;   // MFMA C/D frag

// Truncating fp32 -> (hi, lo) bf16 split: x ≈ hi + lo with |err| ~ 2^-17 |x|.
__device__ inline void f2bf_split(float x, short& hi, short& lo) {
  const unsigned u = __float_as_uint(x);
  hi = (short)(u >> 16);
  const float rem = x - __uint_as_float(u & 0xffff0000u);  // exact
  lo = (short)(__float_as_uint(rem) >> 16);
}

// DPP-based add from a statically-permuted lane (VALU pipe, ~2 cyc latency).
#define DPP_ADD(v, ctrl)                                             \
  ((v) + __int_as_float(__builtin_amdgcn_update_dpp(                 \
             0, __float_as_int(v), (ctrl), 0xF, 0xF, true)))
// Full sum over each 16-lane row: xor1, xor2 (quad_perm), ror8, ror4.
#define REDUCE16(v)            \
  do {                         \
    v = DPP_ADD(v, 0xB1);      \
    v = DPP_ADD(v, 0x4E);      \
    v = DPP_ADD(v, 0x128);     \
    v = DPP_ADD(v, 0x124);     \
  } while (0)

// Cooperative wave-wide lower_bound: first idx with arr[idx] >= target.
// 64 lanes probe a stride grid; ballot+popc shrinks the range ~64x per
// round -> 3 rounds for T=204800 (vs 18 serial dependent loads).
__device__ inline int lower_bound_coop(const int* __restrict__ arr, int n,
                                       int target, int lane) {
  int lo = 0, hi = n;  // invariant: arr[lo-1] < target <= arr[hi]
  while (hi > lo) {
    const int stride = (hi - lo + 63) >> 6;
    const int pos = lo + lane * stride;
    const int v = (pos < hi) ? arr[pos] : 0x7fffffff;
    const unsigned long long m = __ballot(v < target);
    const int cnt = __popcll(m);
    if (cnt == 0) break;  // arr[lo] >= target -> answer = lo
    const int nlo = lo + (cnt - 1) * stride + 1;
    hi = min(lo + cnt * stride, hi);
    lo = nlo;
  }
  return lo;
}

// ---------------------------------------------------------------------------
// Single fused kernel. Block = 1024 threads = 16 waves = 16 candidates
// (grid = B/16 = 256 blocks = 1 block/CU). No workspace, no global M.
// Phase A: per-wave MFMA producer of M (bf16 hi/lo, LDS-bounced frag image).
// Phase B: 16 behavior rows per MFMA tile, DPP dice reductions, prefetched
// behavior loads (1-tile software pipeline).
// ---------------------------------------------------------------------------
__global__ __launch_bounds__(1024) void attention_fused(
    const float* __restrict__ cand, const float* __restrict__ behavior,
    const int* __restrict__ row_ids, const float* __restrict__ W1,
    const float* __restrict__ b1, const float* __restrict__ alpha,
    const float* __restrict__ W2, const float* __restrict__ b2,
    float* __restrict__ out, int T, int B) {
  const int lane = threadIdx.x & 63;
  const int w = threadIdx.x >> 6;  // wave id 0..15: producer q / candidate
  const int r0 = blockIdx.x * 16;
  const int r = r0 + w;
  const int c = lane & 15;  // A-row / C-col index
  const int g = lane >> 4;  // 16-lane group

  __shared__ __align__(16) unsigned short img[16 * 2048];  // 64 KB, 1 plane
  __shared__ int segs[17];

  // ---- segment bounds: cooperative 64-ary search (3 rounds each) ----
  const int t0 = lower_bound_coop(row_ids, T, r, lane);
  if (lane == 0) segs[w] = t0;
  if (w == 15) {
    const int te = lower_bound_coop(row_ids, T, r0 + 16, lane);
    if (lane == 0) segs[16] = te;
  }

  // ---- first-tile prefetch (in flight during Phase A). Guard with T;
  //      exact t1-guard applied after the first barrier. ----
  f32x4 a0 = {0.f, 0.f, 0.f, 0.f}, a1 = {0.f, 0.f, 0.f, 0.f};
  {
    const int trow = t0 + c;
    if (trow < T) {
      const f32x4* bp =
          reinterpret_cast<const f32x4*>(behavior + (size_t)trow * 32 + 8 * g);
      a0 = bp[0];
      a1 = bp[1];
    }
  }

  // ---- Phase A: producer ----
  // A-frag: A[m=c][j=8g+jj] = cand[r0+c][8g+jj]  (hi/lo split)
  bf16x8 Ahi, Alo;
  {
    const f32x4* ap =
        reinterpret_cast<const f32x4*>(cand + (size_t)(r0 + c) * 32 + 8 * g);
    const f32x4 x0 = ap[0], x1 = ap[1];
    const float av[8] = {x0.x, x0.y, x0.z, x0.w, x1.x, x1.y, x1.z, x1.w};
#pragma unroll
    for (int j = 0; j < 8; j++) {
      short h, l;
      f2bf_split(av[j], h, l);
      Ahi[j] = h; Alo[j] = l;
    }
  }

  float v[8][4];  // per-tile C column values (32 VGPRs)
#pragma unroll
  for (int m = 0; m < 8; m++) {
    const int np = 8 * w + m;         // col-tile 0..127
    const int i = np >> 2;            // 0..31
    const int k = 16 * (np & 3) + c;  // 0..63
    // B-frag: B[j=8g+jj][col=c] = W1[(64 + 32*i + 8g + jj)*64 + k]
    const float* bp = W1 + (size_t)(64 + 32 * i + 8 * g) * 64 + k;
    bf16x8 Bh, Bl;
#pragma unroll
    for (int jj = 0; jj < 8; jj++) {
      short h, l;
      f2bf_split(bp[(size_t)jj * 64], h, l);
      Bh[jj] = h; Bl[jj] = l;
    }
    f32x4 Cz = {0.f, 0.f, 0.f, 0.f};
    Cz = __builtin_amdgcn_mfma_f32_16x16x32_bf16(Alo, Bh, Cz, 0, 0, 0);
    Cz = __builtin_amdgcn_mfma_f32_16x16x32_bf16(Ahi, Bl, Cz, 0, 0, 0);
    Cz = __builtin_amdgcn_mfma_f32_16x16x32_bf16(Ahi, Bh, Cz, 0, 0, 0);
    const float bias = W1[(size_t)(32 + i) * 64 + k];  // W1b[i][k]
#pragma unroll
    for (int p = 0; p < 4; p++) v[m][p] = Cz[p] + bias;
  }

  // Frag image staging: hi plane, consume, then lo plane (same 64 KB).
  bf16x8 Bhi[4], Blo[4];
#pragma unroll
  for (int m = 0; m < 8; m++) {
    const int np = 8 * w + m;
    const int base = ((np & 3) * 64 + 16 * (np >> 5) + c) * 8 + ((np >> 2) & 7);
#pragma unroll
    for (int p = 0; p < 4; p++) {
      const unsigned u = __float_as_uint(v[m][p]);
      img[(4 * g + p) * 2048 + base] = (unsigned short)(u >> 16);
    }
  }
  __syncthreads();
#pragma unroll
  for (int n = 0; n < 4; n++)
    Bhi[n] = *reinterpret_cast<const bf16x8*>(&img[w * 2048 + (n * 64 + lane) * 8]);
  __syncthreads();
#pragma unroll
  for (int m = 0; m < 8; m++) {
    const int np = 8 * w + m;
    const int base = ((np & 3) * 64 + 16 * (np >> 5) + c) * 8 + ((np >> 2) & 7);
#pragma unroll
    for (int p = 0; p < 4; p++) {
      const float x = v[m][p];
      const float rem = x - __uint_as_float(__float_as_uint(x) & 0xffff0000u);
      img[(4 * g + p) * 2048 + base] = (unsigned short)(__float_as_uint(rem) >> 16);
    }
  }
  __syncthreads();
#pragma unroll
  for (int n = 0; n < 4; n++)
    Blo[n] = *reinterpret_cast<const bf16x8*>(&img[w * 2048 + (n * 64 + lane) * 8]);

  // ---- per-lane col constants for cols 16n+c ----
  float base_n[4], al_n[4], w2_n[4];
#pragma unroll
  for (int n = 0; n < 4; n++) {
    base_n[n] = b1[16 * n + c];
    al_n[n] = alpha[16 * n + c];
    w2_n[n] = W2[16 * n + c];
  }
  for (int d = 0; d < 32; d++) {
    const float cd = cand[(size_t)r * 32 + d];  // wave-uniform -> s_load
#pragma unroll
    for (int n = 0; n < 4; n++)
      base_n[n] = fmaf(cd, W1[(size_t)d * 64 + 16 * n + c], base_n[n]);
  }
  const float b2v = b2[0];
  const int wsrc = ((c >> 2) << 4) | (c & 3);  // shfl source for w[row=c]

  // t1 from neighbor's boundary (visible since first __syncthreads).
  const int t1 = segs[w + 1];
  // Exact pad-guard for the prefetched first tile.
  if (t0 + c >= t1) {
    a0 = (f32x4){0.f, 0.f, 0.f, 0.f};
    a1 = (f32x4){0.f, 0.f, 0.f, 0.f};
  }

  float acc[8];
#pragma unroll
  for (int jj = 0; jj < 8; jj++) acc[jj] = 0.f;

  // ---- Phase B: attention, 16 rows per tile, 1-tile lookahead ----
  for (int tb = t0; tb < t1; tb += 16) {
    // Prefetch next tile (full tile-compute time + 3 sibling waves to hide).
    f32x4 n0 = {0.f, 0.f, 0.f, 0.f}, n1 = {0.f, 0.f, 0.f, 0.f};
    {
      const int trow = tb + 16 + c;
      if (trow < t1) {
        const f32x4* bp =
            reinterpret_cast<const f32x4*>(behavior + (size_t)trow * 32 + 8 * g);
        n0 = bp[0];
        n1 = bp[1];
      }
    }

    bf16x8 Fhi, Flo;
    {
      const float av[8] = {a0.x, a0.y, a0.z, a0.w, a1.x, a1.y, a1.z, a1.w};
#pragma unroll
      for (int j = 0; j < 8; j++) {
        short h, l;
        f2bf_split(av[j], h, l);
        Fhi[j] = h; Flo[j] = l;
      }
    }

    f32x4 C[4];
#pragma unroll
    for (int n = 0; n < 4; n++) {
      f32x4 cz = {0.f, 0.f, 0.f, 0.f};
      cz = __builtin_amdgcn_mfma_f32_16x16x32_bf16(Flo, Bhi[n], cz, 0, 0, 0);
      cz = __builtin_amdgcn_mfma_f32_16x16x32_bf16(Fhi, Blo[n], cz, 0, 0, 0);
      cz = __builtin_amdgcn_mfma_f32_16x16x32_bf16(Fhi, Bhi[n], cz, 0, 0, 0);
      C[n] = cz;
    }

    // h = C + base; raw moments per row (row = 4g+j).
    float s[4], s2[4];
#pragma unroll
    for (int j = 0; j < 4; j++) {
      float ss = 0.f, qq = 0.f;
#pragma unroll
      for (int n = 0; n < 4; n++) {
        const float h = C[n][j] + base_n[n];
        C[n][j] = h;
        ss += h;
        qq += h * h;
      }
      s[j] = ss;
      s2[j] = qq;
    }
#pragma unroll
    for (int j = 0; j < 4; j++) {
      REDUCE16(s[j]);
      REDUCE16(s2[j]);
    }

    float wp[4];
#pragma unroll
    for (int j = 0; j < 4; j++) {
      const float mean = s[j] * (1.f / 64.f);
      const float var = fmaxf(s2[j] * (1.f / 64.f) - mean * mean, 0.f);
      const float inv = __builtin_amdgcn_rsqf(var + DICE_EPS);
      float ww = 0.f;
#pragma unroll
      for (int n = 0; n < 4; n++) {
        const float h = C[n][j];
        const float e = __expf((mean - h) * inv);
        const float p = __builtin_amdgcn_rcpf(1.f + e);
        const float hd = (al_n[n] + p * (1.f - al_n[n])) * h;
        ww = fmaf(hd, w2_n[n], ww);
      }
      wp[j] = ww;
    }
#pragma unroll
    for (int j = 0; j < 4; j++) REDUCE16(wp[j]);

    // w for row m=c lives in lane group (c>>2) as wp[c&3]: select + shfl.
    const float t01 = (c & 1) ? wp[1] : wp[0];
    const float t23 = (c & 1) ? wp[3] : wp[2];
    const float vsel = (c & 2) ? t23 : t01;
    const float wv = __shfl(vsel, wsrc, 64) + b2v;

    acc[0] = fmaf(a0.x, wv, acc[0]);
    acc[1] = fmaf(a0.y, wv, acc[1]);
    acc[2] = fmaf(a0.z, wv, acc[2]);
    acc[3] = fmaf(a0.w, wv, acc[3]);
    acc[4] = fmaf(a1.x, wv, acc[4]);
    acc[5] = fmaf(a1.y, wv, acc[5]);
    acc[6] = fmaf(a1.z, wv, acc[6]);
    acc[7] = fmaf(a1.w, wv, acc[7]);

    a0 = n0;  // rotate the pipeline
    a1 = n1;
  }

  // Sum over the 16 rows (c-lanes) via DPP, once per candidate.
#pragma unroll
  for (int jj = 0; jj < 8; jj++) REDUCE16(acc[jj]);
  if (c == 0) {  // lanes 0,16,32,48 -> d = 8g .. 8g+7
    f32x4 o0 = {acc[0], acc[1], acc[2], acc[3]};
    f32x4 o1 = {acc[4], acc[5], acc[6], acc[7]};
    f32x4* op = reinterpret_cast<f32x4*>(out + (size_t)r * 32 + 8 * g);
    op[0] = o0;
    op[1] = o1;
  }
}

// ---------------------------------------------------------------------------
extern "C" void kernel_launch(void* const* d_in, const int* in_sizes, int n_in,
                              void* d_out, int out_size, void* d_ws, size_t ws_size,
                              hipStream_t stream) {
  const float* cand     = (const float*)d_in[0];
  const float* behavior = (const float*)d_in[1];
  const int*   row_ids  = (const int*)d_in[2];
  const float* W1       = (const float*)d_in[3];
  const float* b1       = (const float*)d_in[4];
  const float* alpha    = (const float*)d_in[5];
  const float* W2       = (const float*)d_in[6];
  const float* b2       = (const float*)d_in[7];
  float* out = (float*)d_out;

  const int B = in_sizes[0] / 32;  // 4096
  const int T = in_sizes[2];       // 204800

  attention_fused<<<B / 16, 1024, 0, stream>>>(cand, behavior, row_ids, W1, b1,
                                               alpha, W2, b2, out, T, B);
}